// Round 13
// baseline (79.358 us; speedup 1.0000x reference)
//
#include <hip/hip_runtime.h>
#include <cstdint>
#include <cstddef>

#define BB 32
#define SS 1024
#define EE 512
#define UU 512
#define DD 512

typedef unsigned short ushort_t;
typedef __attribute__((ext_vector_type(8))) short s16x8;
typedef __attribute__((ext_vector_type(8))) _Float16 h16x8;
typedef __attribute__((ext_vector_type(4))) float f32x4;

#define AS1(p) ((const __attribute__((address_space(1))) void*)(const void*)(p))
#define AS3(p) ((__attribute__((address_space(3))) void*)(void*)(p))

__device__ inline float fast_tanh(float x) {
    float ax = fminf(fabsf(x), 20.0f);
    float e2 = __expf(ax * 2.0f);
    float t  = 1.0f - __fdividef(2.0f, e2 + 1.0f);
    return (x < 0.0f) ? -t : t;
}

// ---------------- K1: prep (unchanged format) ----------------
// blocks 0..127  : pack Ua into swizzled fp16 staging image UaSwz.
//   Tile (nt,kt) = 128n x 64k. chunk c in tile: n=c>>3, kp=c&7, ko=kp^(n&7).
//   chunk data = fp16(Ua[kt*64+ko*8+j][nt*128+n]), j=0..7  (16B per chunk).
// blocks 128..383: dec_proj = hidden_dec @ Wa  (256 blocks: (b, 64-col slice))
__global__ void prep_kernel(const float* __restrict__ Ua,
                            const float* __restrict__ hid,
                            const float* __restrict__ Wa,
                            ushort_t* __restrict__ UaSwz,
                            float* __restrict__ decp) {
    __shared__ float sm[256];
    int blk = blockIdx.x, t = threadIdx.x;
    if (blk < 128) {
        int g    = blk * 256 + t;       // chunk id 0..32767
        int tile = g >> 10;             // 0..31 = nt*8+kt
        int c    = g & 1023;
        int nt = tile >> 3, kt = tile & 7;
        int n = c >> 3, kp = c & 7;
        int ko = kp ^ (n & 7);
        int u  = nt * 128 + n;
        int e0 = kt * 64 + ko * 8;
        s16x8 v;
#pragma unroll
        for (int j = 0; j < 8; ++j) {
            _Float16 h = (_Float16)Ua[(size_t)(e0 + j) * UU + u];  // RNE, 2^-12
            v[j] = (short)__builtin_bit_cast(unsigned short, h);
        }
        *(s16x8*)(UaSwz + (size_t)g * 8) = v;
    } else {
        int q2 = blk - 128;             // 0..255
        int b = q2 >> 3, q = q2 & 7;
        int uo = t & 63, ch = t >> 6;
        const float* h = hid + (size_t)b * DD;
        float a = 0.f;
        int d0 = ch * 128;
#pragma unroll 4
        for (int d = d0; d < d0 + 128; ++d)
            a = fmaf(h[d], Wa[(size_t)d * UU + q * 64 + uo], a);
        sm[t] = a;
        __syncthreads();
        if (t < 64) {
            float s = sm[t] + sm[64 + t] + sm[128 + t] + sm[192 + t];
            decp[(size_t)b * UU + q * 64 + t] = s;
        }
    }
}

// ---------------- K2: B-stationary scores kernel ----------------
// scpart[q][b][s] = sum_{u in quarter q} tanh((enc[b,s,:]@Ua)[u]+decp[b,u])*Va[u]
// B-quarter (128 cols x K=512 fp16 = 128 KB) lives in LDS for the whole
// kernel: K-loop has zero barriers / zero staging. 256 blocks (1/CU) x 8
// waves; wave owns 64 rows = 4 m-frags -> each B ds_read feeds 4 MFMAs.
// Register contract (r11/r12 lesson): budget = 256 unified/wave at 2
// waves/SIMD, split 128 AGPR (acc[4][8]) + 128 VGPR. The explicit A
// double-buffer (64 VGPR) overflowed the VGPR half -> 38-41 MB scratch
// spill. A is now loaded INLINE per (kt,m) (single-buffered); zero-barrier
// K-loop + 2 free-running waves/SIMD hide the L2 latency instead.
__global__ __launch_bounds__(512, 2)
void scores_kernel(const float* __restrict__ enc,
                   const ushort_t* __restrict__ UaSwz,
                   const float* __restrict__ decp,
                   const float* __restrict__ Va,
                   float* __restrict__ scpart) {
    __shared__ __align__(16) ushort_t lds_b[65536];   // 128 KB: 8 k-tiles [128n][64k]
    __shared__ float lds_dv[256];   // [0..127]=decp slice, [128..255]=Va slice

    const int tid  = threadIdx.x;   // 0..511
    const int lane = tid & 63;
    const int wave = tid >> 6;      // 0..7
    // XCD grouping: the 4 q-blocks of a slice share p&7 -> same XCD L2 for A.
    const int p     = blockIdx.x;
    const int xcd   = p & 7;
    const int i     = p >> 3;             // 0..31
    const int slice = xcd * 8 + (i >> 2); // 0..63  (b, s-half)
    const int q     = i & 3;              // u-quarter
    const int b     = slice >> 1;
    const int half  = slice & 1;

    if (tid < 128)      lds_dv[tid] = decp[(size_t)b * UU + q * 128 + tid];
    else if (tid < 256) lds_dv[tid] = Va[q * 128 + (tid - 128)];

    // ---- B stage (ONCE): copy the q-quarter's 128 KB swizzled image ----
#pragma unroll
    for (int j = 0; j < 16; ++j) {
        __builtin_amdgcn_global_load_lds(
            AS1(UaSwz + (size_t)q * 65536 + ((j * 512 + wave * 64 + lane) * 8)),
            AS3(&lds_b[(j * 512 + wave * 64) * 8]), 16, 0, 0);
    }

    const int nl = lane & 15;
    const int kq = lane >> 4;
    const int l7 = lane & 7;
    // swizzled per-lane read offsets (shorts) for even/odd kt within a k-tile
    const int soff0 = nl * 64 + (((0 + kq) ^ l7) * 8);
    const int soff1 = nl * 64 + (((4 + kq) ^ l7) * 8);

    // wave owns rows [half*512 + wave*64, +64): 4 m-frags of 16
    const float* Abase = enc + ((size_t)b * SS + half * 512 + wave * 64 + nl) * EE
                             + kq * 8;

    f32x4 acc[4][8];
#pragma unroll
    for (int m = 0; m < 4; ++m)
#pragma unroll
        for (int nf = 0; nf < 8; ++nf) acc[m][nf] = f32x4{0.f, 0.f, 0.f, 0.f};

    asm volatile("s_waitcnt vmcnt(0)" ::: "memory");   // own B-writes landed
    __builtin_amdgcn_s_barrier();                      // all waves' B + dv visible

    // ---- K-loop: NO barriers, NO staging, NO explicit dbuf ----
#pragma unroll
    for (int kt = 0; kt < 16; ++kt) {
        h16x8 am[4];
#pragma unroll
        for (int m = 0; m < 4; ++m) {
            f32x4 v0 = *(const f32x4*)(Abase + m * 16 * EE + kt * 32);
            f32x4 v1 = *(const f32x4*)(Abase + m * 16 * EE + kt * 32 + 4);
            h16x8 h;
#pragma unroll
            for (int jj = 0; jj < 4; ++jj) {
                h[jj]     = (_Float16)v0[jj];
                h[4 + jj] = (_Float16)v1[jj];
            }
            am[m] = h;
        }
        const ushort_t* bp = lds_b + (kt >> 1) * 8192 + ((kt & 1) ? soff1 : soff0);
#pragma unroll
        for (int nf = 0; nf < 8; ++nf) {
            h16x8 bh = *(const h16x8*)(bp + nf * 1024);
            acc[0][nf] = __builtin_amdgcn_mfma_f32_16x16x32_f16(am[0], bh, acc[0][nf], 0, 0, 0);
            acc[1][nf] = __builtin_amdgcn_mfma_f32_16x16x32_f16(am[1], bh, acc[1][nf], 0, 0, 0);
            acc[2][nf] = __builtin_amdgcn_mfma_f32_16x16x32_f16(am[2], bh, acc[2][nf], 0, 0, 0);
            acc[3][nf] = __builtin_amdgcn_mfma_f32_16x16x32_f16(am[3], bh, acc[3][nf], 0, 0, 0);
        }
    }

    // ---- epilogue: sp = sum_n tanh(acc + decp)*Va, reduce over 16 col-lanes ----
    // C/D layout: col = lane&15 (n), row = kq*4 + r (within the m-frag)
#pragma unroll
    for (int m = 0; m < 4; ++m) {
        f32x4 sp = {0.f, 0.f, 0.f, 0.f};
#pragma unroll
        for (int nf = 0; nf < 8; ++nf) {
            float dp = lds_dv[nf * 16 + nl];
            float va = lds_dv[128 + nf * 16 + nl];
#pragma unroll
            for (int r = 0; r < 4; ++r)
                sp[r] += fast_tanh(acc[m][nf][r] + dp) * va;
        }
#pragma unroll
        for (int off = 1; off < 16; off <<= 1) {
#pragma unroll
            for (int r = 0; r < 4; ++r)
                sp[r] += __shfl_xor(sp[r], off, 64);
        }
        if (nl == 0) {
            float* o = scpart + ((size_t)q * BB + b) * SS
                     + half * 512 + wave * 64 + m * 16 + kq * 4;
            o[0] = sp[0]; o[1] = sp[1]; o[2] = sp[2]; o[3] = sp[3];
        }
    }
}

// ---------------- K3: fused softmax + context partials ----------------
// block (b, scn): sum the 4 u-quarter score partials, derive row max/sum,
// weight this block's 64-s chunk of enc. 512 blocks.
__global__ void context_partial(const float* __restrict__ enc,
                                const float* __restrict__ scp,  // [4][B][S]
                                float* __restrict__ part) {     // [16][B][E]
    __shared__ float red[8];
    __shared__ float al[64];
    int bid = blockIdx.x;
    int b = bid >> 4, scn = bid & 15;
    int t = threadIdx.x, lane = t & 63, wave = t >> 6;

    f32x4 v = {0.f, 0.f, 0.f, 0.f};
#pragma unroll
    for (int q = 0; q < 4; ++q) {
        f32x4 u = *(const f32x4*)(scp + (size_t)q * BB * SS + (size_t)b * SS + t * 4);
        v[0] += u[0]; v[1] += u[1]; v[2] += u[2]; v[3] += u[3];
    }

    float m = fmaxf(fmaxf(v[0], v[1]), fmaxf(v[2], v[3]));
#pragma unroll
    for (int off = 1; off < 64; off <<= 1) m = fmaxf(m, __shfl_xor(m, off, 64));
    if (lane == 0) red[wave] = m;
    __syncthreads();
    m = fmaxf(fmaxf(red[0], red[1]), fmaxf(red[2], red[3]));

    float e0 = __expf(v[0] - m), e1 = __expf(v[1] - m);
    float e2 = __expf(v[2] - m), e3 = __expf(v[3] - m);
    float s = e0 + e1 + e2 + e3;
#pragma unroll
    for (int off = 1; off < 64; off <<= 1) s += __shfl_xor(s, off, 64);
    if (lane == 0) red[4 + wave] = s;
    __syncthreads();
    s = red[4] + red[5] + red[6] + red[7];
    float inv = 1.0f / s;

    // this block's 64-s chunk: rows scn*64 .. scn*64+63, held by threads
    // [scn*16, scn*16+16), 4 rows each
    if (t >= scn * 16 && t < scn * 16 + 16) {
        int i0 = (t - scn * 16) * 4;
        al[i0 + 0] = e0 * inv; al[i0 + 1] = e1 * inv;
        al[i0 + 2] = e2 * inv; al[i0 + 3] = e3 * inv;
    }
    __syncthreads();

    const float* basep = enc + ((size_t)b * SS + scn * 64) * EE;
    float a0 = 0.f, a1 = 0.f;
#pragma unroll 4
    for (int si = 0; si < 64; ++si) {
        float w = al[si];
        a0 = fmaf(w, basep[(size_t)si * EE + t], a0);
        a1 = fmaf(w, basep[(size_t)si * EE + t + 256], a1);
    }
    float* pp = part + ((size_t)scn * BB + b) * EE;
    pp[t] = a0;
    pp[t + 256] = a1;
}

// ---------------- K4: deterministic reduce of 16 partials ----------------
__global__ void context_reduce(const float* __restrict__ part,
                               float* __restrict__ out) {
    int g = blockIdx.x * 256 + threadIdx.x;  // 0..16383
    float s = 0.f;
#pragma unroll
    for (int scn = 0; scn < 16; ++scn) s += part[(size_t)scn * BB * EE + g];
    out[g] = s;
}

extern "C" void kernel_launch(void* const* d_in, const int* in_sizes, int n_in,
                              void* d_out, int out_size, void* d_ws, size_t ws_size,
                              hipStream_t stream) {
    const float* enc = (const float*)d_in[0];   // [B,S,E]
    const float* hid = (const float*)d_in[1];   // [B,D]
    const float* Wa  = (const float*)d_in[2];   // [D,U]
    const float* Ua  = (const float*)d_in[3];   // [E,U]
    const float* Va  = (const float*)d_in[4];   // [U]
    float* out = (float*)d_out;                 // [B,E]

    // ws layout (part overlaps UaSwz: UaSwz is dead once scores_kernel ends,
    // and prep re-writes it at the start of every call -> deterministic)
    char* ws = (char*)d_ws;
    float*    decp   = (float*)(ws);                  //  64 KB @ 0
    float*    scpart = (float*)(ws + 65536);          // 512 KB  [4][B][S]
    ushort_t* UaSwz  = (ushort_t*)(ws + 589824);      // 512 KB
    float*    part   = (float*)(ws + 589824);         //   1 MB  [16][B][E] (overlap)

    prep_kernel<<<384, 256, 0, stream>>>(Ua, hid, Wa, UaSwz, decp);
    scores_kernel<<<256, 512, 0, stream>>>(enc, UaSwz, decp, Va, scpart);
    context_partial<<<512, 256, 0, stream>>>(enc, scpart, part);
    context_reduce<<<64, 256, 0, stream>>>(part, out);
}

// Round 14
// 70.497 us; speedup vs baseline: 1.1257x; 1.1257x over previous
//
#include <hip/hip_runtime.h>
#include <cstdint>
#include <cstddef>

#define BB 32
#define SS 1024
#define EE 512
#define UU 512
#define DD 512

typedef unsigned short ushort_t;
typedef __attribute__((ext_vector_type(8))) short s16x8;
typedef __attribute__((ext_vector_type(8))) _Float16 h16x8;
typedef __attribute__((ext_vector_type(4))) float f32x4;

#define AS1(p) ((const __attribute__((address_space(1))) void*)(const void*)(p))
#define AS3(p) ((__attribute__((address_space(3))) void*)(void*)(p))

__device__ inline float fast_tanh(float x) {
    float ax = fminf(fabsf(x), 20.0f);
    float e2 = __expf(ax * 2.0f);
    float t  = 1.0f - __fdividef(2.0f, e2 + 1.0f);
    return (x < 0.0f) ? -t : t;
}

// ---------------- K1: prep (unchanged format) ----------------
// blocks 0..127  : pack Ua into swizzled fp16 staging image UaSwz.
//   Tile (nt,kt) = 128n x 64k. chunk c in tile: n=c>>3, kp=c&7, ko=kp^(n&7).
//   chunk data = fp16(Ua[kt*64+ko*8+j][nt*128+n]), j=0..7  (16B per chunk).
// blocks 128..383: dec_proj = hidden_dec @ Wa  (256 blocks: (b, 64-col slice))
__global__ void prep_kernel(const float* __restrict__ Ua,
                            const float* __restrict__ hid,
                            const float* __restrict__ Wa,
                            ushort_t* __restrict__ UaSwz,
                            float* __restrict__ decp) {
    __shared__ float sm[256];
    int blk = blockIdx.x, t = threadIdx.x;
    if (blk < 128) {
        int g    = blk * 256 + t;       // chunk id 0..32767
        int tile = g >> 10;             // 0..31 = nt*8+kt
        int c    = g & 1023;
        int nt = tile >> 3, kt = tile & 7;
        int n = c >> 3, kp = c & 7;
        int ko = kp ^ (n & 7);
        int u  = nt * 128 + n;
        int e0 = kt * 64 + ko * 8;
        s16x8 v;
#pragma unroll
        for (int j = 0; j < 8; ++j) {
            _Float16 h = (_Float16)Ua[(size_t)(e0 + j) * UU + u];  // RNE, 2^-12
            v[j] = (short)__builtin_bit_cast(unsigned short, h);
        }
        *(s16x8*)(UaSwz + (size_t)g * 8) = v;
    } else {
        int q2 = blk - 128;             // 0..255
        int b = q2 >> 3, q = q2 & 7;
        int uo = t & 63, ch = t >> 6;
        const float* h = hid + (size_t)b * DD;
        float a = 0.f;
        int d0 = ch * 128;
#pragma unroll 4
        for (int d = d0; d < d0 + 128; ++d)
            a = fmaf(h[d], Wa[(size_t)d * UU + q * 64 + uo], a);
        sm[t] = a;
        __syncthreads();
        if (t < 64) {
            float s = sm[t] + sm[64 + t] + sm[128 + t] + sm[192 + t];
            decp[(size_t)b * UU + q * 64 + t] = s;
        }
    }
}

// ---------------- K2: B-stationary scores kernel ----------------
// scpart[q][b][s] = sum_{u in quarter q} tanh((enc[b,s,:]@Ua)[u]+decp[b,u])*Va[u]
// B-quarter (128 cols x K=512 fp16 = 128 KB) lives in LDS for the whole
// kernel: K-loop has zero barriers / zero staging. 256 blocks (1/CU) x 8
// waves; wave owns 64 rows = 4 m-frags -> each B ds_read feeds 4 MFMAs.
// r12/r13 lesson: with the kt loop FULLY unrolled and no barriers, the
// compiler pipelines loads across many iterations and overflows the
// 256-unified-reg/wave budget (acc pins 128) -> ~40 MB scratch regardless
// of source-level buffering. unroll 2 bounds the scheduling window (~96
// VGPR of loads in flight) while keeping kt-parity (swizzle offsets)
// compile-time. TLP (2 free-running waves/SIMD) hides L2 latency.
__global__ __launch_bounds__(512, 2)
void scores_kernel(const float* __restrict__ enc,
                   const ushort_t* __restrict__ UaSwz,
                   const float* __restrict__ decp,
                   const float* __restrict__ Va,
                   float* __restrict__ scpart) {
    __shared__ __align__(16) ushort_t lds_b[65536];   // 128 KB: 8 k-tiles [128n][64k]
    __shared__ float lds_dv[256];   // [0..127]=decp slice, [128..255]=Va slice

    const int tid  = threadIdx.x;   // 0..511
    const int lane = tid & 63;
    const int wave = tid >> 6;      // 0..7
    // XCD grouping: the 4 q-blocks of a slice share p&7 -> same XCD L2 for A.
    const int p     = blockIdx.x;
    const int xcd   = p & 7;
    const int i     = p >> 3;             // 0..31
    const int slice = xcd * 8 + (i >> 2); // 0..63  (b, s-half)
    const int q     = i & 3;              // u-quarter
    const int b     = slice >> 1;
    const int half  = slice & 1;

    if (tid < 128)      lds_dv[tid] = decp[(size_t)b * UU + q * 128 + tid];
    else if (tid < 256) lds_dv[tid] = Va[q * 128 + (tid - 128)];

    // ---- B stage (ONCE): copy the q-quarter's 128 KB swizzled image ----
#pragma unroll
    for (int j = 0; j < 16; ++j) {
        __builtin_amdgcn_global_load_lds(
            AS1(UaSwz + (size_t)q * 65536 + ((j * 512 + wave * 64 + lane) * 8)),
            AS3(&lds_b[(j * 512 + wave * 64) * 8]), 16, 0, 0);
    }

    const int nl = lane & 15;
    const int kq = lane >> 4;
    const int l7 = lane & 7;
    // swizzled per-lane read offsets (shorts) for even/odd kt within a k-tile
    const int soff0 = nl * 64 + (((0 + kq) ^ l7) * 8);
    const int soff1 = nl * 64 + (((4 + kq) ^ l7) * 8);

    // wave owns rows [half*512 + wave*64, +64): 4 m-frags of 16
    const float* Abase = enc + ((size_t)b * SS + half * 512 + wave * 64 + nl) * EE
                             + kq * 8;

    f32x4 acc[4][8];
#pragma unroll
    for (int m = 0; m < 4; ++m)
#pragma unroll
        for (int nf = 0; nf < 8; ++nf) acc[m][nf] = f32x4{0.f, 0.f, 0.f, 0.f};

    asm volatile("s_waitcnt vmcnt(0)" ::: "memory");   // own B-writes landed
    __builtin_amdgcn_s_barrier();                      // all waves' B + dv visible

    // ---- K-loop: no barriers/staging; unroll 2 bounds the sched window ----
#pragma unroll 2
    for (int kt = 0; kt < 16; ++kt) {
        h16x8 am[4];
#pragma unroll
        for (int m = 0; m < 4; ++m) {
            f32x4 v0 = *(const f32x4*)(Abase + m * 16 * EE + kt * 32);
            f32x4 v1 = *(const f32x4*)(Abase + m * 16 * EE + kt * 32 + 4);
            h16x8 h;
#pragma unroll
            for (int jj = 0; jj < 4; ++jj) {
                h[jj]     = (_Float16)v0[jj];
                h[4 + jj] = (_Float16)v1[jj];
            }
            am[m] = h;
        }
        const ushort_t* bp = lds_b + (kt >> 1) * 8192 + ((kt & 1) ? soff1 : soff0);
#pragma unroll
        for (int nf = 0; nf < 8; ++nf) {
            h16x8 bh = *(const h16x8*)(bp + nf * 1024);
            acc[0][nf] = __builtin_amdgcn_mfma_f32_16x16x32_f16(am[0], bh, acc[0][nf], 0, 0, 0);
            acc[1][nf] = __builtin_amdgcn_mfma_f32_16x16x32_f16(am[1], bh, acc[1][nf], 0, 0, 0);
            acc[2][nf] = __builtin_amdgcn_mfma_f32_16x16x32_f16(am[2], bh, acc[2][nf], 0, 0, 0);
            acc[3][nf] = __builtin_amdgcn_mfma_f32_16x16x32_f16(am[3], bh, acc[3][nf], 0, 0, 0);
        }
    }

    // ---- epilogue: sp = sum_n tanh(acc + decp)*Va, reduce over 16 col-lanes ----
    // C/D layout: col = lane&15 (n), row = kq*4 + r (within the m-frag)
#pragma unroll
    for (int m = 0; m < 4; ++m) {
        f32x4 sp = {0.f, 0.f, 0.f, 0.f};
#pragma unroll
        for (int nf = 0; nf < 8; ++nf) {
            float dp = lds_dv[nf * 16 + nl];
            float va = lds_dv[128 + nf * 16 + nl];
#pragma unroll
            for (int r = 0; r < 4; ++r)
                sp[r] += fast_tanh(acc[m][nf][r] + dp) * va;
        }
#pragma unroll
        for (int off = 1; off < 16; off <<= 1) {
#pragma unroll
            for (int r = 0; r < 4; ++r)
                sp[r] += __shfl_xor(sp[r], off, 64);
        }
        if (nl == 0) {
            float* o = scpart + ((size_t)q * BB + b) * SS
                     + half * 512 + wave * 64 + m * 16 + kq * 4;
            o[0] = sp[0]; o[1] = sp[1]; o[2] = sp[2]; o[3] = sp[3];
        }
    }
}

// ---------------- K3: fused softmax + context partials ----------------
// block (b, scn): sum the 4 u-quarter score partials, derive row max/sum,
// weight this block's 64-s chunk of enc. 512 blocks.
__global__ void context_partial(const float* __restrict__ enc,
                                const float* __restrict__ scp,  // [4][B][S]
                                float* __restrict__ part) {     // [16][B][E]
    __shared__ float red[8];
    __shared__ float al[64];
    int bid = blockIdx.x;
    int b = bid >> 4, scn = bid & 15;
    int t = threadIdx.x, lane = t & 63, wave = t >> 6;

    f32x4 v = {0.f, 0.f, 0.f, 0.f};
#pragma unroll
    for (int q = 0; q < 4; ++q) {
        f32x4 u = *(const f32x4*)(scp + (size_t)q * BB * SS + (size_t)b * SS + t * 4);
        v[0] += u[0]; v[1] += u[1]; v[2] += u[2]; v[3] += u[3];
    }

    float m = fmaxf(fmaxf(v[0], v[1]), fmaxf(v[2], v[3]));
#pragma unroll
    for (int off = 1; off < 64; off <<= 1) m = fmaxf(m, __shfl_xor(m, off, 64));
    if (lane == 0) red[wave] = m;
    __syncthreads();
    m = fmaxf(fmaxf(red[0], red[1]), fmaxf(red[2], red[3]));

    float e0 = __expf(v[0] - m), e1 = __expf(v[1] - m);
    float e2 = __expf(v[2] - m), e3 = __expf(v[3] - m);
    float s = e0 + e1 + e2 + e3;
#pragma unroll
    for (int off = 1; off < 64; off <<= 1) s += __shfl_xor(s, off, 64);
    if (lane == 0) red[4 + wave] = s;
    __syncthreads();
    s = red[4] + red[5] + red[6] + red[7];
    float inv = 1.0f / s;

    // this block's 64-s chunk: rows scn*64 .. scn*64+63, held by threads
    // [scn*16, scn*16+16), 4 rows each
    if (t >= scn * 16 && t < scn * 16 + 16) {
        int i0 = (t - scn * 16) * 4;
        al[i0 + 0] = e0 * inv; al[i0 + 1] = e1 * inv;
        al[i0 + 2] = e2 * inv; al[i0 + 3] = e3 * inv;
    }
    __syncthreads();

    const float* basep = enc + ((size_t)b * SS + scn * 64) * EE;
    float a0 = 0.f, a1 = 0.f;
#pragma unroll 4
    for (int si = 0; si < 64; ++si) {
        float w = al[si];
        a0 = fmaf(w, basep[(size_t)si * EE + t], a0);
        a1 = fmaf(w, basep[(size_t)si * EE + t + 256], a1);
    }
    float* pp = part + ((size_t)scn * BB + b) * EE;
    pp[t] = a0;
    pp[t + 256] = a1;
}

// ---------------- K4: deterministic reduce of 16 partials ----------------
__global__ void context_reduce(const float* __restrict__ part,
                               float* __restrict__ out) {
    int g = blockIdx.x * 256 + threadIdx.x;  // 0..16383
    float s = 0.f;
#pragma unroll
    for (int scn = 0; scn < 16; ++scn) s += part[(size_t)scn * BB * EE + g];
    out[g] = s;
}

extern "C" void kernel_launch(void* const* d_in, const int* in_sizes, int n_in,
                              void* d_out, int out_size, void* d_ws, size_t ws_size,
                              hipStream_t stream) {
    const float* enc = (const float*)d_in[0];   // [B,S,E]
    const float* hid = (const float*)d_in[1];   // [B,D]
    const float* Wa  = (const float*)d_in[2];   // [D,U]
    const float* Ua  = (const float*)d_in[3];   // [E,U]
    const float* Va  = (const float*)d_in[4];   // [U]
    float* out = (float*)d_out;                 // [B,E]

    // ws layout (part overlaps UaSwz: UaSwz is dead once scores_kernel ends,
    // and prep re-writes it at the start of every call -> deterministic)
    char* ws = (char*)d_ws;
    float*    decp   = (float*)(ws);                  //  64 KB @ 0
    float*    scpart = (float*)(ws + 65536);          // 512 KB  [4][B][S]
    ushort_t* UaSwz  = (ushort_t*)(ws + 589824);      // 512 KB
    float*    part   = (float*)(ws + 589824);         //   1 MB  [16][B][E] (overlap)

    prep_kernel<<<384, 256, 0, stream>>>(Ua, hid, Wa, UaSwz, decp);
    scores_kernel<<<256, 512, 0, stream>>>(enc, UaSwz, decp, Va, scpart);
    context_partial<<<512, 256, 0, stream>>>(enc, scpart, part);
    context_reduce<<<64, 256, 0, stream>>>(part, out);
}